// Round 10
// baseline (40.195 us; speedup 1.0000x reference)
//
#include <hip/hip_runtime.h>
#include <hip/hip_bf16.h>

#define NH 32          // heads
#define NV 1537        // edge_enc_w rows
#define ND 20          // MULTI_HOP_MAX_DIST
#define NB 16          // batch
#define NN 64          // nodes

#define TROWS (ND*NV)                    // 30740
#define TBLOCKS ((TROWS + 31) / 32)      // 961  (32 rows per block)
#define BORDER_N (NB*NH*65 + NB*NH*64)   // 66048
#define BBLOCKS ((BORDER_N + 255) / 256) // 258

#define SLAB_U32 (NV * 8)                // 12296 u32 = 49,184 B per d-slab
#define MAIN_LDS (2*SLAB_U32*4 + 20*1024*2)  // 98,368 + 40,960 = 139,328 B

typedef unsigned int   u32;
typedef unsigned short u16;
typedef __attribute__((ext_vector_type(2))) float f32x2;
typedef __attribute__((ext_vector_type(4))) int   v4i;
typedef __attribute__((ext_vector_type(4))) float v4f;

// ---- fp8 e4m3 helpers (HW cvt; asm fallback keeps the same semantics) ----
__device__ __forceinline__ f32x2 fp8x2_to_f32(u32 u) {
#if __has_builtin(__builtin_amdgcn_cvt_pk_f32_fp8)
    return __builtin_amdgcn_cvt_pk_f32_fp8(u, false);   // decodes bytes 0,1
#else
    f32x2 r;
    asm("v_cvt_pk_f32_fp8 %0, %1" : "=v"(r) : "v"(u));
    return r;
#endif
}
__device__ __forceinline__ u32 f32x4_to_fp8(float a0, float a1, float a2, float a3) {
#if __has_builtin(__builtin_amdgcn_cvt_pk_fp8_f32)
    u32 u = __builtin_amdgcn_cvt_pk_fp8_f32(a0, a1, 0u, false);
    u     = __builtin_amdgcn_cvt_pk_fp8_f32(a2, a3, u,  true);
    return u;
#else
    u32 lo, hi;
    asm("v_cvt_pk_fp8_f32 %0, %1, %2" : "=v"(lo) : "v"(a0), "v"(a1));
    asm("v_cvt_pk_fp8_f32 %0, %1, %2" : "=v"(hi) : "v"(a2), "v"(a3));
    return (lo & 0xffffu) | (hi << 16);
#endif
}

// ---------------- Kernel 1: build T (fp8 e4m3, x256) + borders, fused ----------------
// T row = 32 heads x 1B = 32B = 8 u32. 8 lanes per row, lane l packs heads 4l..4l+3.
__global__ void __launch_bounds__(256)
prep_kernel(const float* __restrict__ enc,     // (1537,32)
            const float* __restrict__ wdis,    // (20,32,32)
            const float* __restrict__ ab,      // (B,65,65)
            const float* __restrict__ tokw,    // (32,)
            u32* __restrict__ T8,              // (30740, 8) u32 out
            float* __restrict__ out) {         // (B,32,65,65)
    int blk = blockIdx.x;
    if (blk < TBLOCKS) {
        int row = blk * 32 + (threadIdx.x >> 3);
        int l   = threadIdx.x & 7;
        if (row >= TROWS) return;
        int d = row / NV, v = row - d * NV;
        const float* e = enc + v * NH;
        const float* w = wdis + d * NH * NH + 4 * l;
        float a0 = 0.f, a1 = 0.f, a2 = 0.f, a3 = 0.f;
#pragma unroll
        for (int k = 0; k < NH; ++k) {
            float ev = e[k];                       // broadcast within row-group
            float4 w4 = *(const float4*)(w + k * NH);  // 8 lanes x 16B = 128B
            a0 += ev * w4.x; a1 += ev * w4.y;
            a2 += ev * w4.z; a3 += ev * w4.w;
        }
        T8[row * 8 + l] = f32x4_to_fp8(a0 * 256.f, a1 * 256.f,
                                       a2 * 256.f, a3 * 256.f);
    } else {
        int t = (blk - TBLOCKS) * 256 + threadIdx.x;
        const int nA = NB * NH * 65;   // row 0, all j
        if (t < nA) {
            int j = t % 65; int bh = t / 65; int h = bh & 31; int b = bh >> 5;
            __builtin_nontemporal_store(2.0f * ab[b * 4225 + j] + tokw[h],
                &out[((size_t)(b * NH + h) * 65 + 0) * 65 + j]);
        } else {
            t -= nA;                   // col 0, i >= 1
            if (t >= NB * NH * 64) return;
            int i = (t % 64) + 1; int bh = t / 64; int h = bh & 31; int b = bh >> 5;
            __builtin_nontemporal_store(2.0f * ab[b * 4225 + i * 65] + tokw[h],
                &out[((size_t)(b * NH + h) * 65 + i) * 65 + 0]);
        }
    }
}

// ---------------- Kernel 2: d-phased LDS-staged gather ----------------
// 256 blocks x 512 threads. Block owns 256 cells (b fixed, 4 i-rows).
// Loop d: double-buffered 49KB fp8 slab in LDS; prefetch d+1 into regs
// BEFORE gather phase, write to other buffer after; 1 barrier per phase.
// Gather: 8 lanes/cell (lane = head-quad), ds_read_b32 from slab.
__global__ void __launch_bounds__(512, 1)
main_kernel(const float* __restrict__ ab,      // (B,65,65)
            const int*   __restrict__ spos,    // (B,64,64)
            const int*   __restrict__ eidx,    // (B,64,64,20,3)
            const float* __restrict__ mask2d,  // (B,)
            const float* __restrict__ spw,     // (512,32)
            const u32*   __restrict__ T8,      // (30740,8) u32 fp8 rows
            float*       __restrict__ out) {   // (B,32,65,65)
    extern __shared__ __align__(16) u32 dyn[];
    u32* slab0 = dyn;                          // [12296]
    u32* slab1 = dyn + SLAB_U32;               // [12296]
    u16* sdx   = (u16*)(dyn + 2 * SLAB_U32);   // [20][256*4] raw idx

    int tid = threadIdx.x;
    int blk = blockIdx.x;                      // 0..255
    int b   = blk >> 4;
    int i0  = (blk & 15) << 2;                 // first of 4 i-rows

    // --- stage edge indices -> sdx[d][cell*4+f] (u16 scatter, one-time) ---
    const v4i* ep4 = (const v4i*)(eidx + (size_t)blk * 256 * 60);   // 3840 v4i
    for (int t = tid; t < 3840; t += 512) {
        v4i q = __builtin_nontemporal_load(ep4 + t);
        int fi = t * 4;
#pragma unroll
        for (int cmp = 0; cmp < 4; ++cmp) {
            int f2   = fi + cmp;
            int cell = f2 / 60;
            int pos  = f2 - cell * 60;
            int d    = pos / 3;
            int f    = pos - d * 3;
            int val  = (cmp == 0) ? q.x : (cmp == 1) ? q.y : (cmp == 2) ? q.z : q.w;
            sdx[d * 1024 + cell * 4 + f] = (u16)val;
        }
    }
    // --- stage slab 0 (streamed, coalesced) ---
    {
        const v4i* g = (const v4i*)T8;
        v4i* s4 = (v4i*)slab0;
#pragma unroll
        for (int p = 0; p < 6; ++p) s4[p * 512 + tid] = g[p * 512 + tid];
        if (tid < 8) slab0[12288 + tid] = T8[12288 + tid];
    }
    __syncthreads();

    int grp = tid >> 3, l = tid & 7;           // cell-slot, head-quad lane
    f32x2 aA0={0,0},aB0={0,0},aA1={0,0},aB1={0,0};
    f32x2 aA2={0,0},aB2={0,0},aA3={0,0},aB3={0,0};

    int cur = 0;
    for (int d = 0; d < ND; ++d) {
        // prefetch next slab into registers (issue-early)
        v4i r0, r1, r2, r3, r4, r5; u32 rt;
        if (d + 1 < ND) {
            const v4i* g = (const v4i*)(T8 + (size_t)(d + 1) * SLAB_U32);
            r0 = g[tid];        r1 = g[512 + tid];  r2 = g[1024 + tid];
            r3 = g[1536 + tid]; r4 = g[2048 + tid]; r5 = g[2560 + tid];
            if (tid < 8) rt = T8[(size_t)(d + 1) * SLAB_U32 + 12288 + tid];
        }
        // gather phase from current slab
        const u32* sb = cur ? slab1 : slab0;
        const u16* sd = sdx + d * 1024;
#pragma unroll
        for (int it = 0; it < 4; ++it) {
            int c = it * 64 + grp;
            ushort4 q = *(const ushort4*)(sd + c * 4);      // ds_read_b64
            u32 v0 = sb[(u32)q.x * 8u + l];
            u32 v1 = sb[(u32)q.y * 8u + l];
            u32 v2 = sb[(u32)q.z * 8u + l];
            f32x2 sA = fp8x2_to_f32(v0) + fp8x2_to_f32(v1) + fp8x2_to_f32(v2);
            f32x2 sB = fp8x2_to_f32(v0 >> 16) + fp8x2_to_f32(v1 >> 16)
                     + fp8x2_to_f32(v2 >> 16);
            if      (it == 0) { aA0 += sA; aB0 += sB; }
            else if (it == 1) { aA1 += sA; aB1 += sB; }
            else if (it == 2) { aA2 += sA; aB2 += sB; }
            else              { aA3 += sA; aB3 += sB; }
        }
        // write prefetched slab (write-late), then one barrier
        if (d + 1 < ND) {
            u32* nb = cur ? slab0 : slab1;
            v4i* s4 = (v4i*)nb;
            s4[tid] = r0;        s4[512 + tid] = r1;  s4[1024 + tid] = r2;
            s4[1536 + tid] = r3; s4[2048 + tid] = r4; s4[2560 + tid] = r5;
            if (tid < 8) nb[12288 + tid] = rt;
        }
        __syncthreads();
        cur ^= 1;
    }

    // epilogue: comb[cell][h] (stride 33) aliased into slab memory
    float* comb = (float*)dyn;                 // 256*33*4 = 33,792 B
    float m = mask2d[b];
#pragma unroll
    for (int it = 0; it < 4; ++it) {
        int c = it * 64 + grp;
        int s = spos[blk * 256 + c];
        int sp = (s == 0) ? 1 : s;
        sp = (sp > 1) ? sp - 1 : sp;
        sp = (sp > ND) ? ND : sp;
        float esc = m / (768.0f * (float)sp);  // /3sp and /256 fp8 scale
        v4f spv = ((const v4f*)(spw + s * NH))[l];
        f32x2 A  = (it == 0) ? aA0 : (it == 1) ? aA1 : (it == 2) ? aA2 : aA3;
        f32x2 Bv = (it == 0) ? aB0 : (it == 1) ? aB1 : (it == 2) ? aB2 : aB3;
        comb[c * 33 + 4 * l + 0] = spv.x * m + A.x  * esc;
        comb[c * 33 + 4 * l + 1] = spv.y * m + A.y  * esc;
        comb[c * 33 + 4 * l + 2] = spv.z * m + Bv.x * esc;
        comb[c * 33 + 4 * l + 3] = spv.w * m + Bv.y * esc;
    }
    __syncthreads();

    // write out: 16 values/thread, 64 consecutive j per wave -> 256B lines
#pragma unroll
    for (int w = 0; w < 16; ++w) {
        int idx = w * 512 + tid;
        int j = idx & 63, h = (idx >> 6) & 31, r = idx >> 11;
        float a2b = 2.0f * ab[(b * 65 + i0 + r + 1) * 65 + (j + 1)];
        __builtin_nontemporal_store(a2b + comb[(r * 64 + j) * 33 + h],
            &out[(((size_t)b * NH + h) * 65 + i0 + r + 1) * 65 + (j + 1)]);
    }
}

extern "C" void kernel_launch(void* const* d_in, const int* in_sizes, int n_in,
                              void* d_out, int out_size, void* d_ws, size_t ws_size,
                              hipStream_t stream) {
    const float* attn_bias   = (const float*)d_in[0];
    const int*   spatial_pos = (const int*)  d_in[1];
    // d_in[2] = x (unused), d_in[4] = attn_edge_type (unused)
    const int*   edge_input  = (const int*)  d_in[3];
    const float* mask_2d     = (const float*)d_in[5];
    const float* edge_enc_w  = (const float*)d_in[6];
    const float* edge_dis_w  = (const float*)d_in[7];
    const float* spatial_w   = (const float*)d_in[8];
    const float* token_w     = (const float*)d_in[9];
    float* out = (float*)d_out;
    u32* T8 = (u32*)d_ws;   // 30740 * 32B = 983,680 B

    // Kernel 1: build T (fp8) + borders
    prep_kernel<<<TBLOCKS + BBLOCKS, 256, 0, stream>>>(edge_enc_w, edge_dis_w,
                                                       attn_bias, token_w, T8, out);
    // Kernel 2: d-phased LDS-staged gather (dynamic LDS = 139,328 B)
    main_kernel<<<256, 512, MAIN_LDS, stream>>>(attn_bias, spatial_pos, edge_input,
                                                mask_2d, spatial_w, T8, out);
}

// Round 11
// 30.618 us; speedup vs baseline: 1.3128x; 1.3128x over previous
//
#include <hip/hip_runtime.h>
#include <hip/hip_bf16.h>

#define NH 32          // heads
#define NV 1537        // edge_enc_w rows
#define ND 20          // MULTI_HOP_MAX_DIST
#define NB 16          // batch
#define NN 64          // nodes

#define ENC_U32 (NV*8)                   // 12296 u32 (fp8 enc, 32 B/row)
#define WDT_U32 (ND*NH*NH/2)             // 10240 u32 (bf16 WdT, [d][h][k])
#define CVT1_BLOCKS ((ENC_U32 + 255)/256)            // 49
#define CVT2_BLOCKS (WDT_U32/256)                    // 40
#define BORDER_N (NB*NH*65 + NB*NH*64)               // 66048
#define BBLOCKS ((BORDER_N + 255)/256)               // 258

// main-kernel LDS layout (bytes)
#define LDS_ENC  0
#define LDS_WDT  49184                   // = ENC_U32*4
#define LDS_SDX  90144                   // = LDS_WDT + WDT_U32*4
#define LDS_SPOS 131104                  // = LDS_SDX + 256*80*2
#define MAIN_LDS 132128                  // + 256*4

typedef unsigned int   u32;
typedef unsigned short u16;
typedef __attribute__((ext_vector_type(2))) float        f32x2;
typedef __attribute__((ext_vector_type(4))) float        f32x4;
typedef __attribute__((ext_vector_type(2))) unsigned int u32x2;
typedef __attribute__((ext_vector_type(4))) unsigned int u32x4;
typedef __attribute__((ext_vector_type(4))) int          v4i;
typedef __attribute__((ext_vector_type(8))) short        bf16x8_t;

// ---- fp8 e4m3 helpers (proven R7-R9) ----
__device__ __forceinline__ f32x2 fp8x2_to_f32(u32 u) {
#if __has_builtin(__builtin_amdgcn_cvt_pk_f32_fp8)
    return __builtin_amdgcn_cvt_pk_f32_fp8(u, false);
#else
    f32x2 r;
    asm("v_cvt_pk_f32_fp8 %0, %1" : "=v"(r) : "v"(u));
    return r;
#endif
}
__device__ __forceinline__ u32 f32x4_to_fp8(float a0, float a1, float a2, float a3) {
#if __has_builtin(__builtin_amdgcn_cvt_pk_fp8_f32)
    u32 u = __builtin_amdgcn_cvt_pk_fp8_f32(a0, a1, 0u, false);
    u     = __builtin_amdgcn_cvt_pk_fp8_f32(a2, a3, u,  true);
    return u;
#else
    u32 lo, hi;
    asm("v_cvt_pk_fp8_f32 %0, %1, %2" : "=v"(lo) : "v"(a0), "v"(a1));
    asm("v_cvt_pk_fp8_f32 %0, %1, %2" : "=v"(hi) : "v"(a2), "v"(a3));
    return (lo & 0xffffu) | (hi << 16);
#endif
}
__device__ __forceinline__ u32 pk_bf16(float lo, float hi) {
    u32 r;
    asm("v_cvt_pk_bf16_f32 %0, %1, %2" : "=v"(r) : "v"(lo), "v"(hi));
    return r;
}

// ---------------- Kernel 1: enc->fp8, Wd->bf16^T, borders ----------------
__global__ void __launch_bounds__(256)
prep_kernel(const float* __restrict__ enc,     // (1537,32)
            const float* __restrict__ wdis,    // (20,32,32)
            const float* __restrict__ ab,      // (B,65,65)
            const float* __restrict__ tokw,    // (32,)
            u32* __restrict__ enc8g,           // (12296,) fp8x4, x256 scale
            u32* __restrict__ wdtg,            // (10240,) bf16x2, [d][h][k]
            float* __restrict__ out) {         // (B,32,65,65)
    int blk = blockIdx.x, tid = threadIdx.x;
    if (blk < CVT1_BLOCKS) {
        int o = blk * 256 + tid;               // u32 index: v = o>>3, kg = o&7
        if (o < ENC_U32) {
            float4 e = *(const float4*)(enc + o * 4);
            enc8g[o] = f32x4_to_fp8(e.x * 256.f, e.y * 256.f,
                                    e.z * 256.f, e.w * 256.f);
        }
    } else if (blk < CVT1_BLOCKS + CVT2_BLOCKS) {
        int o = (blk - CVT1_BLOCKS) * 256 + tid;   // < 10240
        int d = o >> 9, rem = o & 511;
        int h = rem >> 4, kp = rem & 15;           // k-pair
        const float* ws = wdis + d * 1024 + h;
        float lo = ws[(2 * kp) * 32];
        float hi = ws[(2 * kp + 1) * 32];
        wdtg[o] = pk_bf16(lo, hi);
    } else {
        int t = (blk - CVT1_BLOCKS - CVT2_BLOCKS) * 256 + tid;
        const int nA = NB * NH * 65;           // row 0, all j
        if (t < nA) {
            int j = t % 65; int bh = t / 65; int h = bh & 31; int b = bh >> 5;
            __builtin_nontemporal_store(2.0f * ab[b * 4225 + j] + tokw[h],
                &out[((size_t)(b * NH + h) * 65 + 0) * 65 + j]);
        } else {
            t -= nA;                           // col 0, i >= 1
            if (t >= NB * NH * 64) return;
            int i = (t % 64) + 1; int bh = t / 64; int h = bh & 31; int b = bh >> 5;
            __builtin_nontemporal_store(2.0f * ab[b * 4225 + i * 65] + tokw[h],
                &out[((size_t)(b * NH + h) * 65 + i) * 65 + 0]);
        }
    }
}

// ---------------- Kernel 2: LDS-gather + MFMA contraction ----------------
// 256 blocks x 512 thr (8 waves). Block owns 256 cells (b, 4 i-rows).
// enc-fp8 (49KB) + WdT-bf16 (40KB) static in LDS; gathers = ds_read_b64.
// Wave handles 2 tiles of 16 cells; per d: A = sum of 3 enc rows (bf16),
// 2x mfma_f32_16x16x32_bf16 (heads 0-15, 16-31). No barriers in d-loop.
__global__ void __launch_bounds__(512, 1)
main_kernel(const float* __restrict__ ab,      // (B,65,65)
            const int*   __restrict__ spos,    // (B,64,64)
            const int*   __restrict__ eidx,    // (B,64,64,20,3)
            const float* __restrict__ mask2d,  // (B,)
            const float* __restrict__ spw,     // (512,32)
            const u32*   __restrict__ enc8g,   // fp8 enc (contiguous with wdtg)
            float*       __restrict__ out) {   // (B,32,65,65)
    extern __shared__ __align__(16) char dyn[];
    char* encB0 = dyn + LDS_ENC;
    char* wdtL  = dyn + LDS_WDT;
    u16*  sdx   = (u16*)(dyn + LDS_SDX);       // [256 cells][20 d][4] (f pad)
    int*  sposL = (int*)(dyn + LDS_SPOS);

    int tid = threadIdx.x, blk = blockIdx.x;
    int b = blk >> 4, i0 = (blk & 15) << 2;

    // --- prologue: copy enc8+wdT (contiguous 22536 u32) into LDS ---
    {
        const u32x4* g = (const u32x4*)enc8g;
        u32x4* s = (u32x4*)dyn;
        for (int p = tid; p < (ENC_U32 + WDT_U32) / 4; p += 512) s[p] = g[p];
    }
    // --- stage edge indices: 256 cells x 60 -> sdx[cell][d][4] u16 ---
    const v4i* ep4 = (const v4i*)(eidx + (size_t)blk * 256 * 60);
    for (int t = tid; t < 3840; t += 512) {
        v4i q = __builtin_nontemporal_load(ep4 + t);
        int base = t * 4;
#pragma unroll
        for (int c = 0; c < 4; ++c) {
            int f2 = base + c;
            int cell = f2 / 60, pos = f2 - cell * 60;
            int d = pos / 3, f = pos - d * 3;
            int val = (c == 0) ? q.x : (c == 1) ? q.y : (c == 2) ? q.z : q.w;
            sdx[cell * 80 + d * 4 + f] = (u16)val;
        }
    }
    if (tid < 256) sposL[tid] = spos[blk * 256 + tid];
    __syncthreads();

    // --- compute: wave wv owns tiles 2wv, 2wv+1 ---
    int wv = tid >> 6, l = tid & 63;
    int c16 = l & 15, g = l >> 4;              // A/B row|col, k-group
    int t0 = wv * 2;

    const char* encB = encB0 + g * 8;          // + q*32 per gather
    const char* wdB1 = wdtL + c16 * 64 + g * 16;
    const char* wdB2 = wdtL + (c16 + 16) * 64 + g * 16;
    const u16* sdx0 = sdx + (t0 * 16 + c16) * 80;
    const u16* sdx1 = sdx + ((t0 + 1) * 16 + c16) * 80;

    f32x4 acc[2][2] = {};                      // [tile][head-half]

    for (int d = 0; d < ND; ++d) {
        bf16x8_t b1 = *(const bf16x8_t*)(wdB1 + d * 2048);
        bf16x8_t b2 = *(const bf16x8_t*)(wdB2 + d * 2048);
#pragma unroll
        for (int t = 0; t < 2; ++t) {
            const u16* sx = t ? sdx1 : sdx0;
            ushort4 q = *(const ushort4*)(sx + d * 4);
            u32x2 e0 = *(const u32x2*)(encB + ((u32)q.x << 5));
            u32x2 e1 = *(const u32x2*)(encB + ((u32)q.y << 5));
            u32x2 e2 = *(const u32x2*)(encB + ((u32)q.z << 5));
            f32x2 s0 = fp8x2_to_f32(e0.x) + fp8x2_to_f32(e1.x) + fp8x2_to_f32(e2.x);
            f32x2 s1 = fp8x2_to_f32(e0.x >> 16) + fp8x2_to_f32(e1.x >> 16)
                     + fp8x2_to_f32(e2.x >> 16);
            f32x2 s2 = fp8x2_to_f32(e0.y) + fp8x2_to_f32(e1.y) + fp8x2_to_f32(e2.y);
            f32x2 s3 = fp8x2_to_f32(e0.y >> 16) + fp8x2_to_f32(e1.y >> 16)
                     + fp8x2_to_f32(e2.y >> 16);
            union { u32 w[4]; bf16x8_t v; } au;
            au.w[0] = pk_bf16(s0.x, s0.y);
            au.w[1] = pk_bf16(s1.x, s1.y);
            au.w[2] = pk_bf16(s2.x, s2.y);
            au.w[3] = pk_bf16(s3.x, s3.y);
            acc[t][0] = __builtin_amdgcn_mfma_f32_16x16x32_bf16(au.v, b1, acc[t][0], 0, 0, 0);
            acc[t][1] = __builtin_amdgcn_mfma_f32_16x16x32_bf16(au.v, b2, acc[t][1], 0, 0, 0);
        }
    }

    __syncthreads();                           // sdx dead; alias comb over it
    float* comb = (float*)(dyn + LDS_SDX);     // [256 cells][33]
    float m = mask2d[b];
#pragma unroll
    for (int t = 0; t < 2; ++t) {
#pragma unroll
        for (int r = 0; r < 4; ++r) {
            int cell = (t0 + t) * 16 + g * 4 + r;   // D: row=(l>>4)*4+r
            int s = sposL[cell];
            int sp = (s == 0) ? 1 : s;
            sp = (sp > 1) ? sp - 1 : sp;
            sp = (sp > ND) ? ND : sp;
            float esc = m / (768.0f * (float)sp);   // 256 fp8 x 3 mean
            float spbL = spw[s * NH + c16];          // D: col=l&15 -> head
            float spbH = spw[s * NH + c16 + 16];
            comb[cell * 33 + c16]      = spbL * m + acc[t][0][r] * esc;
            comb[cell * 33 + c16 + 16] = spbH * m + acc[t][1][r] * esc;
        }
    }
    __syncthreads();

    // --- write out: 4 i-rows x 32 h x 64 j, 256B-coalesced over j ---
#pragma unroll
    for (int w = 0; w < 16; ++w) {
        int idx = w * 512 + tid;
        int j = idx & 63, h = (idx >> 6) & 31, r = idx >> 11;
        float av = ab[(b * 65 + i0 + r + 1) * 65 + (j + 1)];
        __builtin_nontemporal_store(2.0f * av + comb[(r * 64 + j) * 33 + h],
            &out[(((size_t)b * NH + h) * 65 + i0 + r + 1) * 65 + (j + 1)]);
    }
}

extern "C" void kernel_launch(void* const* d_in, const int* in_sizes, int n_in,
                              void* d_out, int out_size, void* d_ws, size_t ws_size,
                              hipStream_t stream) {
    const float* attn_bias   = (const float*)d_in[0];
    const int*   spatial_pos = (const int*)  d_in[1];
    // d_in[2] = x (unused), d_in[4] = attn_edge_type (unused)
    const int*   edge_input  = (const int*)  d_in[3];
    const float* mask_2d     = (const float*)d_in[5];
    const float* edge_enc_w  = (const float*)d_in[6];
    const float* edge_dis_w  = (const float*)d_in[7];
    const float* spatial_w   = (const float*)d_in[8];
    const float* token_w     = (const float*)d_in[9];
    float* out = (float*)d_out;
    u32* enc8g = (u32*)d_ws;             // 12296 u32
    u32* wdtg  = enc8g + ENC_U32;        // 10240 u32, contiguous

    // Kernel 1: converts + borders
    prep_kernel<<<CVT1_BLOCKS + CVT2_BLOCKS + BBLOCKS, 256, 0, stream>>>(
        edge_enc_w, edge_dis_w, attn_bias, token_w, enc8g, wdtg, out);
    // Kernel 2: LDS-gather + MFMA (dynamic LDS = 132,128 B)
    main_kernel<<<256, 512, MAIN_LDS, stream>>>(attn_bias, spatial_pos, edge_input,
                                                mask_2d, spatial_w, enc8g, out);
}